// Round 9
// baseline (394.743 us; speedup 1.0000x reference)
//
#include <hip/hip_runtime.h>

#define PBLK 256

typedef __attribute__((ext_vector_type(8))) short bf16x8;
typedef __attribute__((ext_vector_type(16))) float f32x16;

struct IPerm { int v[12]; };   // up to 3 perms x 4 atoms (inverse perms)

__device__ __forceinline__ unsigned short f2bf(float x) {
    unsigned int u = __builtin_bit_cast(unsigned int, x);
    u += 0x7fffu + ((u >> 16) & 1u);
    return (unsigned short)(u >> 16);
}

// ---- pre-pass 1: node_reps fp32 -> bf16 ----
__global__ void conv_node(const float* __restrict__ x, unsigned short* __restrict__ o, int n4) {
    int tid = blockIdx.x * PBLK + threadIdx.x;
    if (tid >= n4) return;
    const float4 v = reinterpret_cast<const float4*>(x)[tid];
    ushort4 r;
    r.x = f2bf(v.x); r.y = f2bf(v.y); r.z = f2bf(v.z); r.w = f2bf(v.w);
    reinterpret_cast<ushort4*>(o)[tid] = r;
}

// ---- pre-pass 2: pack w1 into per-perm 32x32x16 B-fragment layout ----
// o[(((p*4+ct)*KS + s)*64 + l)*8 + j]; lane l -> col = ct*32+(l&31),
// k = s*16 + (l>>5)*8 + j; source row permuted per inverse perm on 128-blocks.
// (HW-verified correct in round 5.)
template<int K>
__global__ void pack_w1(const float* __restrict__ w1, unsigned short* __restrict__ o,
                        int nperms, IPerm ip) {
    constexpr int KS = K / 16;
    const int per = K * 128;
    int tid = blockIdx.x * PBLK + threadIdx.x;
    if (tid >= nperms * per) return;
    const int p = tid / per;
    const int e = tid - p * per;
    const int j = e & 7;
    const int l = (e >> 3) & 63;
    const int cts = e >> 9;            // ct*KS + s
    const int s  = cts % KS;
    const int ct = cts / KS;
    const int col = ct * 32 + (l & 31);
    const int k = s * 16 + (l >> 5) * 8 + j;
    const int srow = ip.v[p * 4 + (k >> 7)] * 128 + (k & 127);
    o[tid] = f2bf(w1[(size_t)srow * 128 + col]);
}

// ---- async global->LDS, 16B per lane ----
__device__ __forceinline__ void gld_lds16(const unsigned short* g, unsigned char* l) {
    typedef __attribute__((address_space(1))) unsigned int GU;
    typedef __attribute__((address_space(3))) unsigned int LU;
    __builtin_amdgcn_global_load_lds((GU*)g, (LU*)l, 16, 0, 0);
}

// forced-wide 16B global load: asm "=v" output must stay live from issue to
// use, so a batch of these allocates distinct quads and ALL fly concurrently.
template<int OFF>
__device__ __forceinline__ void glb16(bf16x8& d, const unsigned short* p) {
    if constexpr (OFF == 0)
        asm volatile("global_load_dwordx4 %0, %1, off" : "=v"(d) : "v"(p));
    else
        asm volatile("global_load_dwordx4 %0, %1, off offset:%2" : "=v"(d) : "v"(p), "i"(OFF));
}

// ---- main term kernel ----
// ROWS=64 rows/block, 512 threads = 8 waves (2 row-grp x 4 col-grp), wave tile
// 32 rows x 32 cols, mfma_f32_32x32x16_bf16. X staged per-atom via
// global_load_lds (16KB double-buffer). Per atom the NPERMS*8 B-fragments are
// issued as one inline-asm batch (single latency bubble), then:
// vmcnt(0) -> sched_barrier -> s_barrier -> ds_read+MFMA -> lgkmcnt -> s_barrier
// -> STAGE(a+2). The barrier sits AFTER the drain so all waves' glds for the
// buffer are complete at the barrier (vmcnt is per-wave).
template<int NATOMS, int NPERMS, int DOUT>
__global__ __launch_bounds__(512, 2) void term_mfma(
    const unsigned short* __restrict__ nodeb,  // (N,128) bf16
    const int* __restrict__ idx,               // (nrows,NATOMS) or nullptr
    const unsigned short* __restrict__ pack,   // NPERMS*K*128 bf16 packed
    const float* __restrict__ b1,              // (128)
    const float* __restrict__ w2,              // (128,DOUT)
    const float* __restrict__ b2,              // (DOUT)
    float* __restrict__ out,                   // (nrows,DOUT)
    int nrows)
{
    constexpr int ROWS = 64;
    constexpr int KS   = NATOMS * 8;           // total k-steps of 16
    constexpr int ABUF = ROWS * 256;           // 16KB per atom buffer
    __shared__ __align__(16) unsigned char lds[2 * ABUF];   // 32KB (h reuses)

    const int t    = threadIdx.x;
    const int l    = t & 63;
    const int w    = t >> 6;
    const int hi32 = l >> 5;
    const int l31  = l & 31;
    const int rg   = w >> 2;
    const int cg   = w & 3;
    const int r0   = blockIdx.x * ROWS;
    const int rb   = w * 8;

    // prefetch gather indices into registers
    int nrow_r[NATOMS * 2];
    #pragma unroll
    for (int a = 0; a < NATOMS; ++a)
        #pragma unroll
        for (int q = 0; q < 2; ++q) {
            const int rl = rb + q * 4 + (l >> 4);
            int row = r0 + rl; if (row >= nrows) row = nrows - 1;
            nrow_r[a * 2 + q] = idx ? idx[row * NATOMS + a] : row;
        }

#define STAGE(A, BSEL) do {                                                          \
    unsigned char* buf_ = lds + (BSEL) * ABUF;                                       \
    _Pragma("unroll")                                                                \
    for (int q_ = 0; q_ < 2; ++q_) {                                                 \
        const int rl_ = rb + q_ * 4 + (l >> 4);                                      \
        const unsigned short* src_ = nodeb + (size_t)nrow_r[(A) * 2 + q_] * 128      \
                                     + (((l & 15) ^ (rl_ & 15)) << 3);               \
        gld_lds16(src_, buf_ + (rb + q_ * 4) * 256);                                 \
    } } while (0)

    const int col = cg * 32 + l31;
    const float bv = b1[col];
    f32x16 acc[NPERMS];
    #pragma unroll
    for (int p = 0; p < NPERMS; ++p)
        #pragma unroll
        for (int i = 0; i < 16; ++i) acc[p][i] = bv;

    STAGE(0, 0);
    if (NATOMS > 1) STAGE(1, 1);

    #pragma unroll
    for (int a = 0; a < NATOMS; ++a) {
        // ---- forced-wide B batch: all NPERMS*8 loads in flight at once ----
        bf16x8 B[NPERMS * 8];
        #pragma unroll
        for (int p = 0; p < NPERMS; ++p) {
            const unsigned short* bp0 = pack
                + (((size_t)(p * 4 + cg) * KS + a * 8) * 64 + l) * 8;
            const unsigned short* bp1 = bp0 + 2048;   // +4 k-steps (4096 B)
            glb16<0>   (B[p * 8 + 0], bp0);
            glb16<1024>(B[p * 8 + 1], bp0);
            glb16<2048>(B[p * 8 + 2], bp0);
            glb16<3072>(B[p * 8 + 3], bp0);
            glb16<0>   (B[p * 8 + 4], bp1);
            glb16<1024>(B[p * 8 + 5], bp1);
            glb16<2048>(B[p * 8 + 6], bp1);
            glb16<3072>(B[p * 8 + 7], bp1);
        }
        asm volatile("s_waitcnt vmcnt(0)" ::: "memory");   // B + own glds done
        __builtin_amdgcn_sched_barrier(0);                  // rule 18 fence
        __builtin_amdgcn_s_barrier();                       // all waves' glds done

        const unsigned char* xb = lds + (a & 1) * ABUF;
        const int rowb = rg * 32 + l31;
        #pragma unroll
        for (int s = 0; s < 8; ++s) {
            const bf16x8 av = *reinterpret_cast<const bf16x8*>(
                xb + rowb * 256 + (((s * 2 + hi32) ^ (l & 15)) << 4));
            #pragma unroll
            for (int p = 0; p < NPERMS; ++p)
                acc[p] = __builtin_amdgcn_mfma_f32_32x32x16_bf16(av, B[p * 8 + s], acc[p], 0, 0, 0);
        }
        asm volatile("s_waitcnt lgkmcnt(0)" ::: "memory");  // ds_reads retired
        __builtin_amdgcn_s_barrier();                       // reads done -> refill ok
        if (a + 2 < NATOMS) STAGE(a + 2, a & 1);
    }
#undef STAGE

    // ---- h = sum_p relu(acc_p) -> LDS (fp32, swizzled); C layout per m74/m101 ----
    float* hs = reinterpret_cast<float*>(lds);
    #pragma unroll
    for (int i = 0; i < 16; ++i) {
        const int rowl = rg * 32 + (i & 3) + 8 * (i >> 2) + 4 * hi32;
        float v = 0.0f;
        #pragma unroll
        for (int p = 0; p < NPERMS; ++p) v += fmaxf(acc[p][i], 0.0f);
        hs[rowl * 128 + (col ^ ((rowl & 7) << 2))] = v;
    }
    __syncthreads();

    // ---- layer 2: y = h @ w2 + NPERMS*b2 ----
    if (t < ROWS * DOUT) {
        const int r = t / DOUT;
        const int o = t - r * DOUT;
        float y0 = 0.f, y1 = 0.f, y2 = 0.f, y3 = 0.f;
        #pragma unroll 4
        for (int c = 0; c < 128; c += 4) {
            y0 += hs[r * 128 + ((c    ) ^ ((r & 7) << 2))] * w2[(size_t)(c    ) * DOUT + o];
            y1 += hs[r * 128 + ((c + 1) ^ ((r & 7) << 2))] * w2[(size_t)(c + 1) * DOUT + o];
            y2 += hs[r * 128 + ((c + 2) ^ ((r & 7) << 2))] * w2[(size_t)(c + 2) * DOUT + o];
            y3 += hs[r * 128 + ((c + 3) ^ ((r & 7) << 2))] * w2[(size_t)(c + 3) * DOUT + o];
        }
        const float y = b2[o] * (float)NPERMS + ((y0 + y1) + (y2 + y3));
        const int row = r0 + r;
        if (row < nrows) out[(size_t)row * DOUT + o] = y;
    }
}

extern "C" void kernel_launch(void* const* d_in, const int* in_sizes, int n_in,
                              void* d_out, int out_size, void* d_ws, size_t ws_size,
                              hipStream_t stream) {
    const float* node = (const float*)d_in[0];
    const int* bidx = (const int*)d_in[1];
    const int* gidx = (const int*)d_in[2];
    const int* pidx = (const int*)d_in[3];
    const int* iidx = (const int*)d_in[4];

    const float* aw1 = (const float*)d_in[5];
    const float* ab1 = (const float*)d_in[6];
    const float* aw2 = (const float*)d_in[7];
    const float* ab2 = (const float*)d_in[8];
    const float* bw1 = (const float*)d_in[9];
    const float* bb1 = (const float*)d_in[10];
    const float* bw2 = (const float*)d_in[11];
    const float* bb2 = (const float*)d_in[12];
    const float* gw1 = (const float*)d_in[13];
    const float* gb1 = (const float*)d_in[14];
    const float* gw2 = (const float*)d_in[15];
    const float* gb2 = (const float*)d_in[16];
    const float* pw1 = (const float*)d_in[17];
    const float* pb1 = (const float*)d_in[18];
    const float* pw2 = (const float*)d_in[19];
    const float* pb2 = (const float*)d_in[20];
    const float* iw1 = (const float*)d_in[21];
    const float* ib1 = (const float*)d_in[22];
    const float* iw2 = (const float*)d_in[23];
    const float* ib2 = (const float*)d_in[24];

    const int N  = in_sizes[0] / 128;
    const int NB = in_sizes[1] / 2;
    const int NA = in_sizes[2] / 3;
    const int NP = in_sizes[3] / 4;
    const int NI = in_sizes[4] / 4;

    float* out   = (float*)d_out;
    float* out_a = out;
    float* out_b = out_a + (size_t)N  * 2;
    float* out_g = out_b + (size_t)NB * 2;
    float* out_p = out_g + (size_t)NA * 2;
    float* out_i = out_p + (size_t)NP * 6;

    // ---- workspace layout (bf16 elements) ----
    unsigned short* nodeb = (unsigned short*)d_ws;
    size_t off = (size_t)N * 128;
    unsigned short* packA = nodeb + off; off += (size_t)1 * 128 * 128;
    unsigned short* packB = nodeb + off; off += (size_t)2 * 256 * 128;
    unsigned short* packG = nodeb + off; off += (size_t)2 * 384 * 128;
    unsigned short* packP = nodeb + off; off += (size_t)2 * 512 * 128;
    unsigned short* packI = nodeb + off; off += (size_t)3 * 512 * 128;

    // ---- pre-pass: convert node, pack weights ----
    {
        const int n4 = N * 128 / 4;
        conv_node<<<(n4 + PBLK - 1) / PBLK, PBLK, 0, stream>>>(node, nodeb, n4);
    }
    IPerm ipa{{0,0,0,0,  0,0,0,0,  0,0,0,0}};
    IPerm ipb{{0,1,0,0,  1,0,0,0,  0,0,0,0}};
    IPerm ipg{{0,1,2,0,  2,1,0,0,  0,0,0,0}};
    IPerm ipp{{0,1,2,3,  3,2,1,0,  0,0,0,0}};
    IPerm ipi{{0,1,2,3,  3,1,0,2,  2,1,3,0}};   // inverses of (0123),(2130),(3102)

    pack_w1<128><<<(1 * 128 * 128 + PBLK - 1) / PBLK, PBLK, 0, stream>>>(aw1, packA, 1, ipa);
    pack_w1<256><<<(2 * 256 * 128 + PBLK - 1) / PBLK, PBLK, 0, stream>>>(bw1, packB, 2, ipb);
    pack_w1<384><<<(2 * 384 * 128 + PBLK - 1) / PBLK, PBLK, 0, stream>>>(gw1, packG, 2, ipg);
    pack_w1<512><<<(2 * 512 * 128 + PBLK - 1) / PBLK, PBLK, 0, stream>>>(pw1, packP, 2, ipp);
    pack_w1<512><<<(3 * 512 * 128 + PBLK - 1) / PBLK, PBLK, 0, stream>>>(iw1, packI, 3, ipi);

    // ---- term kernels ----
    term_mfma<1, 1, 2><<<(N  + 63) / 64, 512, 0, stream>>>(nodeb, nullptr, packA, ab1, aw2, ab2, out_a, N);
    term_mfma<2, 2, 2><<<(NB + 63) / 64, 512, 0, stream>>>(nodeb, bidx,    packB, bb1, bw2, bb2, out_b, NB);
    term_mfma<3, 2, 2><<<(NA + 63) / 64, 512, 0, stream>>>(nodeb, gidx,    packG, gb1, gw2, gb2, out_g, NA);
    term_mfma<4, 2, 6><<<(NP + 63) / 64, 512, 0, stream>>>(nodeb, pidx,    packP, pb1, pw2, pb2, out_p, NP);
    term_mfma<4, 3, 6><<<(NI + 63) / 64, 512, 0, stream>>>(nodeb, iidx,    packI, ib1, iw2, ib2, out_i, NI);
}

// Round 10
// 325.599 us; speedup vs baseline: 1.2124x; 1.2124x over previous
//
#include <hip/hip_runtime.h>

#define PBLK 256

typedef __attribute__((ext_vector_type(8))) short bf16x8;
typedef __attribute__((ext_vector_type(16))) float f32x16;

__device__ __forceinline__ unsigned short f2bf(float x) {
    unsigned int u = __builtin_bit_cast(unsigned int, x);
    u += 0x7fffu + ((u >> 16) & 1u);
    return (unsigned short)(u >> 16);
}

// ---- pre-pass 1: node_reps fp32 -> bf16 ----
__global__ void conv_node(const float* __restrict__ x, unsigned short* __restrict__ o, int n4) {
    int tid = blockIdx.x * PBLK + threadIdx.x;
    if (tid >= n4) return;
    const float4 v = reinterpret_cast<const float4*>(x)[tid];
    ushort4 r;
    r.x = f2bf(v.x); r.y = f2bf(v.y); r.z = f2bf(v.z); r.w = f2bf(v.w);
    reinterpret_cast<ushort4*>(o)[tid] = r;
}

// ---- pre-pass 2: pack w1 (K x 128) into SINGLE-copy 32x32x16 B-frag layout ----
// o[((ct*KS + s)*64 + l)*8 + j]; lane l -> col = ct*32+(l&31), k = s*16+(l>>5)*8+j.
// No perm duplication: weight block b is shared across perms (the A-slot changes).
// (Layout HW-verified round 5/7.)
template<int K>
__global__ void pack_w1(const float* __restrict__ w1, unsigned short* __restrict__ o) {
    constexpr int KS = K / 16;
    int tid = blockIdx.x * PBLK + threadIdx.x;
    if (tid >= K * 128) return;
    const int j = tid & 7;
    const int l = (tid >> 3) & 63;
    const int cts = tid >> 9;          // ct*KS + s
    const int s  = cts % KS;
    const int ct = cts / KS;
    const int col = ct * 32 + (l & 31);
    const int k = s * 16 + (l >> 5) * 8 + j;
    o[tid] = f2bf(w1[(size_t)k * 128 + col]);
}

// ---- async global->LDS, 16B per lane ----
__device__ __forceinline__ void gld_lds16(const unsigned short* g, unsigned char* l) {
    typedef __attribute__((address_space(1))) unsigned int GU;
    typedef __attribute__((address_space(3))) unsigned int LU;
    __builtin_amdgcn_global_load_lds((GU*)g, (LU*)l, 16, 0, 0);
}

// forced-wide 16B global load (asm "=v": value stays live issue->use)
template<int OFF>
__device__ __forceinline__ void glb16(bf16x8& d, const unsigned short* p) {
    if constexpr (OFF == 0)
        asm volatile("global_load_dwordx4 %0, %1, off" : "=v"(d) : "v"(p));
    else
        asm volatile("global_load_dwordx4 %0, %1, off offset:%2" : "=v"(d) : "v"(p), "i"(OFF));
}

// ---- per-term config: forward perms (weight block b multiplies x-slot P[p][b]) ----
template<int TERM> struct TC;
template<> struct TC<0> { static constexpr int NA = 1, NP = 1, DO = 2;
                          static constexpr int P[1][4] = {{0,0,0,0}}; };
template<> struct TC<1> { static constexpr int NA = 2, NP = 2, DO = 2;
                          static constexpr int P[2][4] = {{0,1,0,0},{1,0,0,0}}; };
template<> struct TC<2> { static constexpr int NA = 3, NP = 2, DO = 2;
                          static constexpr int P[2][4] = {{0,1,2,0},{2,1,0,0}}; };
template<> struct TC<3> { static constexpr int NA = 4, NP = 2, DO = 6;
                          static constexpr int P[2][4] = {{0,1,2,3},{3,2,1,0}}; };
template<> struct TC<4> { static constexpr int NA = 4, NP = 3, DO = 6;
                          static constexpr int P[3][4] = {{0,1,2,3},{2,1,3,0},{3,1,0,2}}; };

// ---- main term kernel ----
// 64 rows/block, 512 threads = 8 waves (2 rg x 4 cg), wave tile 32x32,
// mfma_f32_32x32x16_bf16. FULL X (all atom slots) staged in prologue via one
// glds burst + one __syncthreads (the only gather drain). K-loop is
// barrier-free; the vmcnt FIFO then contains ONLY the asm B-loads, so a
// counted vmcnt(4) double-buffer (4-frag chunks) actually pipelines. Weight
// block b is loaded once and MFMA'd against NPERMS A-slots (perm-sharing).
template<int TERM>
__global__ __launch_bounds__(512, 4) void term_mfma(
    const unsigned short* __restrict__ nodeb,  // (N,128) bf16
    const int* __restrict__ idx,               // (nrows,NATOMS) or nullptr
    const unsigned short* __restrict__ pack,   // K*128 bf16 packed (single copy)
    const float* __restrict__ b1,              // (128)
    const float* __restrict__ w2,              // (128,DOUT)
    const float* __restrict__ b2,              // (DOUT)
    float* __restrict__ out,                   // (nrows,DOUT)
    int nrows)
{
    constexpr int NATOMS = TC<TERM>::NA;
    constexpr int NPERMS = TC<TERM>::NP;
    constexpr int DOUT   = TC<TERM>::DO;
    constexpr int KS8    = NATOMS * 8;         // total k-steps of 16
    constexpr int NCH    = NATOMS * 2;         // 4-frag B chunks
    constexpr int XB     = NATOMS * 16384;
    constexpr int LB     = XB > 32768 ? XB : 32768;
    __shared__ __align__(16) unsigned char lds[LB];

    const int t    = threadIdx.x;
    const int l    = t & 63;
    const int w    = t >> 6;
    const int hi32 = l >> 5;
    const int l31  = l & 31;
    const int rg   = w >> 2;
    const int cg   = w & 3;
    const int r0   = blockIdx.x * 64;
    const int rb   = w * 8;                    // this wave's 8 staging rows

    // gather indices for this wave's staging rows
    int nrow_r[NATOMS * 2];
    #pragma unroll
    for (int a = 0; a < NATOMS; ++a)
        #pragma unroll
        for (int q = 0; q < 2; ++q) {
            const int rl = rb + q * 4 + (l >> 4);
            int row = r0 + rl; if (row >= nrows) row = nrows - 1;
            nrow_r[a * 2 + q] = idx ? idx[row * NATOMS + a] : row;
        }

    // ---- prologue: burst-stage ALL atom slots (linear dest, pre-swizzled src) ----
    #pragma unroll
    for (int a = 0; a < NATOMS; ++a)
        #pragma unroll
        for (int q = 0; q < 2; ++q) {
            const int rl = rb + q * 4 + (l >> 4);
            const unsigned short* src = nodeb + (size_t)nrow_r[a * 2 + q] * 128
                                        + (((l & 15) ^ (rl & 15)) << 3);
            gld_lds16(src, lds + a * 16384 + (rb + q * 4) * 256);
        }

    const int col = cg * 32 + l31;
    const float bv = b1[col];
    f32x16 acc[NPERMS];
    #pragma unroll
    for (int p = 0; p < NPERMS; ++p)
        #pragma unroll
        for (int i = 0; i < 16; ++i) acc[p][i] = bv;

    // B chunk = 4 k-steps of one weight block (4KB span: offsets 0..3072)
    bf16x8 Ba[4], Bb[4];
#define ISSUEB(R, C) do {                                                          \
    const unsigned short* bp_ = pack                                               \
        + (((size_t)cg * KS8 + ((C) >> 1) * 8 + ((C) & 1) * 4) * 64 + l) * 8;      \
    glb16<0>(R[0], bp_);  glb16<1024>(R[1], bp_);                                  \
    glb16<2048>(R[2], bp_); glb16<3072>(R[3], bp_); } while (0)

    ISSUEB(Ba, 0);
    __syncthreads();   // drains prologue glds (+B_0, once) ; X fully resident

    const int rowb = rg * 32 + l31;
    #pragma unroll
    for (int c = 0; c < NCH; ++c) {
        if (c + 1 < NCH) { if (c & 1) ISSUEB(Ba, c + 1); else ISSUEB(Bb, c + 1); }
        if (c + 1 < NCH) asm volatile("s_waitcnt vmcnt(4)" ::: "memory");
        else             asm volatile("s_waitcnt vmcnt(0)" ::: "memory");
        __builtin_amdgcn_sched_barrier(0);     // rule 18: no MFMA above the wait
        const int a = c >> 1, sh = c & 1;
        #pragma unroll
        for (int s4 = 0; s4 < 4; ++s4) {
            const int ks = sh * 4 + s4;        // k-step within the 128-block
            #pragma unroll
            for (int p = 0; p < NPERMS; ++p) {
                const int slot = TC<TERM>::P[p][a];    // compile-time
                const bf16x8 av = *reinterpret_cast<const bf16x8*>(
                    lds + slot * 16384 + rowb * 256 + (((ks * 2 + hi32) ^ (l & 15)) << 4));
                acc[p] = __builtin_amdgcn_mfma_f32_32x32x16_bf16(
                    av, (c & 1) ? Bb[s4] : Ba[s4], acc[p], 0, 0, 0);
            }
        }
    }
#undef ISSUEB
    __builtin_amdgcn_sched_barrier(0);         // keep layer-2 loads out of the ledger

    __syncthreads();   // all waves done reading X -> reuse LDS for h

    // ---- h = sum_p relu(acc_p) -> LDS (fp32, swizzled); C layout per m74/m101 ----
    float* hs = reinterpret_cast<float*>(lds);
    #pragma unroll
    for (int i = 0; i < 16; ++i) {
        const int rowl = rg * 32 + (i & 3) + 8 * (i >> 2) + 4 * hi32;
        float v = 0.0f;
        #pragma unroll
        for (int p = 0; p < NPERMS; ++p) v += fmaxf(acc[p][i], 0.0f);
        hs[rowl * 128 + (col ^ ((rowl & 7) << 2))] = v;
    }
    __syncthreads();

    // ---- layer 2: y = h @ w2 + NPERMS*b2 ----
    if (t < 64 * DOUT) {
        const int r = t / DOUT;
        const int o = t - r * DOUT;
        float y0 = 0.f, y1 = 0.f, y2 = 0.f, y3 = 0.f;
        #pragma unroll 4
        for (int c = 0; c < 128; c += 4) {
            y0 += hs[r * 128 + ((c    ) ^ ((r & 7) << 2))] * w2[(size_t)(c    ) * DOUT + o];
            y1 += hs[r * 128 + ((c + 1) ^ ((r & 7) << 2))] * w2[(size_t)(c + 1) * DOUT + o];
            y2 += hs[r * 128 + ((c + 2) ^ ((r & 7) << 2))] * w2[(size_t)(c + 2) * DOUT + o];
            y3 += hs[r * 128 + ((c + 3) ^ ((r & 7) << 2))] * w2[(size_t)(c + 3) * DOUT + o];
        }
        const float y = b2[o] * (float)NPERMS + ((y0 + y1) + (y2 + y3));
        const int row = r0 + r;
        if (row < nrows) out[(size_t)row * DOUT + o] = y;
    }
}

extern "C" void kernel_launch(void* const* d_in, const int* in_sizes, int n_in,
                              void* d_out, int out_size, void* d_ws, size_t ws_size,
                              hipStream_t stream) {
    const float* node = (const float*)d_in[0];
    const int* bidx = (const int*)d_in[1];
    const int* gidx = (const int*)d_in[2];
    const int* pidx = (const int*)d_in[3];
    const int* iidx = (const int*)d_in[4];

    const float* aw1 = (const float*)d_in[5];
    const float* ab1 = (const float*)d_in[6];
    const float* aw2 = (const float*)d_in[7];
    const float* ab2 = (const float*)d_in[8];
    const float* bw1 = (const float*)d_in[9];
    const float* bb1 = (const float*)d_in[10];
    const float* bw2 = (const float*)d_in[11];
    const float* bb2 = (const float*)d_in[12];
    const float* gw1 = (const float*)d_in[13];
    const float* gb1 = (const float*)d_in[14];
    const float* gw2 = (const float*)d_in[15];
    const float* gb2 = (const float*)d_in[16];
    const float* pw1 = (const float*)d_in[17];
    const float* pb1 = (const float*)d_in[18];
    const float* pw2 = (const float*)d_in[19];
    const float* pb2 = (const float*)d_in[20];
    const float* iw1 = (const float*)d_in[21];
    const float* ib1 = (const float*)d_in[22];
    const float* iw2 = (const float*)d_in[23];
    const float* ib2 = (const float*)d_in[24];

    const int N  = in_sizes[0] / 128;
    const int NB = in_sizes[1] / 2;
    const int NA = in_sizes[2] / 3;
    const int NP = in_sizes[3] / 4;
    const int NI = in_sizes[4] / 4;

    float* out   = (float*)d_out;
    float* out_a = out;
    float* out_b = out_a + (size_t)N  * 2;
    float* out_g = out_b + (size_t)NB * 2;
    float* out_p = out_g + (size_t)NA * 2;
    float* out_i = out_p + (size_t)NP * 6;

    // ---- workspace layout (bf16 elements) ----
    unsigned short* nodeb = (unsigned short*)d_ws;
    size_t off = (size_t)N * 128;
    unsigned short* packA = nodeb + off; off += (size_t)128 * 128;
    unsigned short* packB = nodeb + off; off += (size_t)256 * 128;
    unsigned short* packG = nodeb + off; off += (size_t)384 * 128;
    unsigned short* packP = nodeb + off; off += (size_t)512 * 128;
    unsigned short* packI = nodeb + off; off += (size_t)512 * 128;

    // ---- pre-pass: convert node, pack weights (single copies) ----
    {
        const int n4 = N * 128 / 4;
        conv_node<<<(n4 + PBLK - 1) / PBLK, PBLK, 0, stream>>>(node, nodeb, n4);
    }
    pack_w1<128><<<(128 * 128 + PBLK - 1) / PBLK, PBLK, 0, stream>>>(aw1, packA);
    pack_w1<256><<<(256 * 128 + PBLK - 1) / PBLK, PBLK, 0, stream>>>(bw1, packB);
    pack_w1<384><<<(384 * 128 + PBLK - 1) / PBLK, PBLK, 0, stream>>>(gw1, packG);
    pack_w1<512><<<(512 * 128 + PBLK - 1) / PBLK, PBLK, 0, stream>>>(pw1, packP);
    pack_w1<512><<<(512 * 128 + PBLK - 1) / PBLK, PBLK, 0, stream>>>(iw1, packI);

    // ---- term kernels ----
    term_mfma<0><<<(N  + 63) / 64, 512, 0, stream>>>(nodeb, nullptr, packA, ab1, aw2, ab2, out_a, N);
    term_mfma<1><<<(NB + 63) / 64, 512, 0, stream>>>(nodeb, bidx,    packB, bb1, bw2, bb2, out_b, NB);
    term_mfma<2><<<(NA + 63) / 64, 512, 0, stream>>>(nodeb, gidx,    packG, gb1, gw2, gb2, out_g, NA);
    term_mfma<3><<<(NP + 63) / 64, 512, 0, stream>>>(nodeb, pidx,    packP, pb1, pw2, pb2, out_p, NP);
    term_mfma<4><<<(NI + 63) / 64, 512, 0, stream>>>(nodeb, iidx,    packI, ib1, iw2, ib2, out_i, NI);
}

// Round 12
// 257.944 us; speedup vs baseline: 1.5303x; 1.2623x over previous
//
#include <hip/hip_runtime.h>

#define PBLK 256

typedef __attribute__((ext_vector_type(8))) short bf16x8;
typedef __attribute__((ext_vector_type(16))) float f32x16;

__device__ __forceinline__ unsigned short f2bf(float x) {
    unsigned int u = __builtin_bit_cast(unsigned int, x);
    u += 0x7fffu + ((u >> 16) & 1u);
    return (unsigned short)(u >> 16);
}

// ---- pre-pass 1: node_reps fp32 -> bf16 ----
__global__ void conv_node(const float* __restrict__ x, unsigned short* __restrict__ o, int n4) {
    int tid = blockIdx.x * PBLK + threadIdx.x;
    if (tid >= n4) return;
    const float4 v = reinterpret_cast<const float4*>(x)[tid];
    ushort4 r;
    r.x = f2bf(v.x); r.y = f2bf(v.y); r.z = f2bf(v.z); r.w = f2bf(v.w);
    reinterpret_cast<ushort4*>(o)[tid] = r;
}

// ---- pre-pass 2: pack w1 (K x 128) into SINGLE-copy 32x32x16 B-frag layout ----
// o[((ct*KS + s)*64 + l)*8 + j]; lane l -> col = ct*32+(l&31), k = s*16+(l>>5)*8+j.
template<int K>
__global__ void pack_w1(const float* __restrict__ w1, unsigned short* __restrict__ o) {
    constexpr int KS = K / 16;
    int tid = blockIdx.x * PBLK + threadIdx.x;
    if (tid >= K * 128) return;
    const int j = tid & 7;
    const int l = (tid >> 3) & 63;
    const int cts = tid >> 9;
    const int s  = cts % KS;
    const int ct = cts / KS;
    const int col = ct * 32 + (l & 31);
    const int k = s * 16 + (l >> 5) * 8 + j;
    o[tid] = f2bf(w1[(size_t)k * 128 + col]);
}

// ---- pre-pass 3: pack all w2 (128 x DOUT) into 32x32x16 B-frag layout, cols>=DOUT zero ----
__global__ void pack_w2_all(const float* __restrict__ wa, const float* __restrict__ wb,
                            const float* __restrict__ wg, const float* __restrict__ wp,
                            const float* __restrict__ wi,
                            unsigned short* __restrict__ oa, unsigned short* __restrict__ ob,
                            unsigned short* __restrict__ og, unsigned short* __restrict__ op,
                            unsigned short* __restrict__ oi) {
    int tid = blockIdx.x * PBLK + threadIdx.x;
    if (tid >= 5 * 4096) return;
    const int term = tid >> 12, e = tid & 4095;
    const float* w; unsigned short* o; int dout;
    switch (term) {
        case 0: w = wa; o = oa; dout = 2; break;
        case 1: w = wb; o = ob; dout = 2; break;
        case 2: w = wg; o = og; dout = 2; break;
        case 3: w = wp; o = op; dout = 6; break;
        default: w = wi; o = oi; dout = 6; break;
    }
    const int j = e & 7, l = (e >> 3) & 63, s = e >> 9;
    const int col = l & 31;
    const int k = s * 16 + (l >> 5) * 8 + j;
    o[e] = (col < dout) ? f2bf(w[k * dout + col]) : (unsigned short)0;
}

// ---- async global->LDS, 16B per lane ----
__device__ __forceinline__ void gld_lds16(const unsigned short* g, unsigned char* l) {
    typedef __attribute__((address_space(1))) unsigned int GU;
    typedef __attribute__((address_space(3))) unsigned int LU;
    __builtin_amdgcn_global_load_lds((GU*)g, (LU*)l, 16, 0, 0);
}

// forced-wide 16B global load (asm "=v": value live issue->use; asm-volatile
// mutual order is preserved, which the vmcnt ledger relies on)
template<int OFF>
__device__ __forceinline__ void glb16(bf16x8& d, const unsigned short* p) {
    if constexpr (OFF == 0)
        asm volatile("global_load_dwordx4 %0, %1, off" : "=v"(d) : "v"(p));
    else
        asm volatile("global_load_dwordx4 %0, %1, off offset:%2" : "=v"(d) : "v"(p), "i"(OFF));
}

template<int N> __device__ __forceinline__ void waitvm() {
    if constexpr (N == 0)       asm volatile("s_waitcnt vmcnt(0)"  ::: "memory");
    else if constexpr (N == 1)  asm volatile("s_waitcnt vmcnt(1)"  ::: "memory");
    else if constexpr (N == 2)  asm volatile("s_waitcnt vmcnt(2)"  ::: "memory");
    else if constexpr (N == 3)  asm volatile("s_waitcnt vmcnt(3)"  ::: "memory");
    else if constexpr (N == 4)  asm volatile("s_waitcnt vmcnt(4)"  ::: "memory");
    else if constexpr (N == 5)  asm volatile("s_waitcnt vmcnt(5)"  ::: "memory");
    else if constexpr (N == 6)  asm volatile("s_waitcnt vmcnt(6)"  ::: "memory");
    else if constexpr (N == 7)  asm volatile("s_waitcnt vmcnt(7)"  ::: "memory");
    else if constexpr (N == 8)  asm volatile("s_waitcnt vmcnt(8)"  ::: "memory");
    else if constexpr (N == 9)  asm volatile("s_waitcnt vmcnt(9)"  ::: "memory");
    else if constexpr (N == 10) asm volatile("s_waitcnt vmcnt(10)" ::: "memory");
    else if constexpr (N == 11) asm volatile("s_waitcnt vmcnt(11)" ::: "memory");
    else if constexpr (N == 12) asm volatile("s_waitcnt vmcnt(12)" ::: "memory");
    else                        asm volatile("s_waitcnt vmcnt(0)"  ::: "memory");
}

// ---- per-term config: weight block b multiplies x-slot P[p][b] ----
template<int TERM> struct TC;
template<> struct TC<0> { static constexpr int NA = 1, NP = 1, DO = 2;
                          static constexpr int P[1][4] = {{0,0,0,0}}; };
template<> struct TC<1> { static constexpr int NA = 2, NP = 2, DO = 2;
                          static constexpr int P[2][4] = {{0,1,0,0},{1,0,0,0}}; };
template<> struct TC<2> { static constexpr int NA = 3, NP = 2, DO = 2;
                          static constexpr int P[2][4] = {{0,1,2,0},{2,1,0,0}}; };
template<> struct TC<3> { static constexpr int NA = 4, NP = 2, DO = 6;
                          static constexpr int P[2][4] = {{0,1,2,3},{3,2,1,0}}; };
template<> struct TC<4> { static constexpr int NA = 4, NP = 3, DO = 6;
                          static constexpr int P[3][4] = {{0,1,2,3},{2,1,3,0},{3,1,0,2}}; };

// ---- main term kernel ----
// Persistent grid-stride over 32-row tiles, 256 threads = 4 waves (ct 0..3),
// wave tile 32 rows x 32 cols, mfma_f32_32x32x16_bf16. K-loop vmcnt FIFO
// contains ONLY the asm B-loads (pure ledger, VWAIT = NA*min(7-C,3)); the
// next tile's gather (glds) is issued in the epilogue when the FIFO is empty,
// flies across raw barrier B (no drain), hides under h-write + layer-2, and
// is drained by waitvm<0> + barrier C before the next tile's LDS reads.
// ks-major loop: per k-step, NA B-blocks loaded once + NA A-slots read once,
// shared across perms. Layer-2 = 8 MFMAs on bf16 h (A-frag layout in LDS)
// against pre-packed w2.
template<int TERM>
__global__ __launch_bounds__(256, 2) void term_mfma(
    const unsigned short* __restrict__ nodeb,  // (N,128) bf16
    const int* __restrict__ idx,               // (nrows,NA) or nullptr
    const unsigned short* __restrict__ pack,   // K*128 bf16 (single copy)
    const unsigned short* __restrict__ pk2,    // 8*64*8 bf16 packed w2
    const float* __restrict__ b1,              // (128)
    const float* __restrict__ b2,              // (DOUT)
    float* __restrict__ out,                   // (nrows,DOUT)
    int nrows, int ntiles)
{
    constexpr int NA   = TC<TERM>::NA;
    constexpr int NP   = TC<TERM>::NP;
    constexpr int DOUT = TC<TERM>::DO;
    constexpr int BUF  = NA * 8192;            // 32 rows x 256B per slot
    __shared__ __align__(16) unsigned char lds[2 * BUF];

    const int t    = threadIdx.x;
    const int l    = t & 63;
    const int w    = t >> 6;                   // wave id = col tile
    const int l31  = l & 31;
    const int hi   = l >> 5;
    const int l15  = l & 15;
    const int qr   = l >> 4;
    const int rowb = l31;
    const int GS   = gridDim.x;

    // static B base pointers: block b, k-half h
    const unsigned short* pbp[NA][2];
    #pragma unroll
    for (int b = 0; b < NA; ++b)
        #pragma unroll
        for (int h = 0; h < 2; ++h)
            pbp[b][h] = pack + (((size_t)w * (NA * 8) + b * 8 + h * 4) * 64 + l) * 8;

    const int col = w * 32 + l31;
    const float bv = b1[col];
    const float b2v = (l31 < DOUT) ? b2[l31] * (float)NP : 0.0f;

    int nrw[NA * 2];
    int tile = blockIdx.x;

    // ---- prologue: gather tile0 into buf0 ----
    #pragma unroll
    for (int a = 0; a < NA; ++a)
        #pragma unroll
        for (int q = 0; q < 2; ++q) {
            const int rl = w * 8 + q * 4 + qr;
            int gr = tile * 32 + rl; if (gr >= nrows) gr = nrows - 1;
            nrw[a * 2 + q] = idx ? idx[gr * NA + a] : gr;
        }
    #pragma unroll
    for (int a = 0; a < NA; ++a)
        #pragma unroll
        for (int q = 0; q < 2; ++q) {
            const int rl = w * 8 + q * 4 + qr;
            gld_lds16(nodeb + (size_t)nrw[a * 2 + q] * 128 + ((l15 ^ (rl & 15)) << 3),
                      lds + a * 8192 + (w * 8 + q * 4) * 256);
        }
    waitvm<0>();
    __builtin_amdgcn_s_barrier();

    int cur = 0;
    for (; tile < ntiles; tile += GS) {
        const bool hasnext = (tile + GS) < ntiles;
        unsigned char* xb = lds + cur * BUF;
        unsigned char* ob = lds + (cur ^ 1) * BUF;

        if (hasnext) {                         // next tile's gather indices
            #pragma unroll
            for (int a = 0; a < NA; ++a)
                #pragma unroll
                for (int q = 0; q < 2; ++q) {
                    const int rl = w * 8 + q * 4 + qr;
                    int gr = (tile + GS) * 32 + rl; if (gr >= nrows) gr = nrows - 1;
                    nrw[a * 2 + q] = idx ? idx[gr * NA + a] : gr;
                }
        }

        f32x16 acc[NP];
        #pragma unroll
        for (int p = 0; p < NP; ++p)
            #pragma unroll
            for (int i = 0; i < 16; ++i) acc[p][i] = bv;

        bf16x8 Bf[4][NA];
#define ISSUEB(J) do { _Pragma("unroll")                                           \
        for (int b = 0; b < NA; ++b)                                               \
            glb16<((J) & 3) * 1024>(Bf[(J) & 3][b], pbp[b][(J) >> 2]); } while (0)

        ISSUEB(0); ISSUEB(1); ISSUEB(2); ISSUEB(3);

#define KSTEP(C) do {                                                              \
        waitvm<NA * (((7 - (C)) < 3) ? (7 - (C)) : 3)>();                          \
        __builtin_amdgcn_sched_barrier(0);                                         \
        bf16x8 av[NA];                                                             \
        _Pragma("unroll")                                                          \
        for (int s = 0; s < NA; ++s)                                               \
            av[s] = *reinterpret_cast<const bf16x8*>(                              \
                xb + s * 8192 + rowb * 256 + ((((C) * 2 + hi) ^ (rowb & 15)) << 4)); \
        _Pragma("unroll")                                                          \
        for (int b = 0; b < NA; ++b) {                                             \
            _Pragma("unroll")                                                      \
            for (int p = 0; p < NP; ++p)                                           \
                acc[p] = __builtin_amdgcn_mfma_f32_32x32x16_bf16(                  \
                    av[TC<TERM>::P[p][b]], Bf[(C) & 3][b], acc[p], 0, 0, 0);       \
        }                                                                          \
        if constexpr ((C) + 4 <= 7) ISSUEB((C) + 4);                               \
    } while (0)

        KSTEP(0); KSTEP(1); KSTEP(2); KSTEP(3);
        KSTEP(4); KSTEP(5); KSTEP(6); KSTEP(7);
#undef KSTEP
#undef ISSUEB

        __builtin_amdgcn_s_barrier();          // A: all waves done reading xb

        // ---- G: next tile's gather -> ob (FIFO empty here; flies across B) ----
        if (hasnext) {
            #pragma unroll
            for (int a = 0; a < NA; ++a)
                #pragma unroll
                for (int q = 0; q < 2; ++q) {
                    const int rl = w * 8 + q * 4 + qr;
                    gld_lds16(nodeb + (size_t)nrw[a * 2 + q] * 128 + ((l15 ^ (rl & 15)) << 3),
                              ob + a * 8192 + (w * 8 + q * 4) * 256);
                }
        }

        // ---- h = sum_p relu(acc_p) -> bf16 in xb, A-frag layout ----
        #pragma unroll
        for (int i = 0; i < 16; ++i) {
            const int rowl = (i & 3) + 8 * (i >> 2) + 4 * hi;
            float v = 0.0f;
            #pragma unroll
            for (int p = 0; p < NP; ++p) v += fmaxf(acc[p][i], 0.0f);
            *reinterpret_cast<unsigned short*>(
                xb + rowl * 256 + (((col >> 3) ^ (rowl & 15)) << 4) + (col & 7) * 2) = f2bf(v);
        }
        asm volatile("s_waitcnt lgkmcnt(0)" ::: "memory");
        __builtin_amdgcn_s_barrier();          // B: h visible (G still in flight)

        // ---- layer 2: y = h @ w2 via 8 MFMAs (all waves compute, w0 stores) ----
        {
            f32x16 a2;
            #pragma unroll
            for (int i = 0; i < 16; ++i) a2[i] = 0.0f;
            #pragma unroll
            for (int s = 0; s < 8; ++s) {
                const bf16x8 ah = *reinterpret_cast<const bf16x8*>(
                    xb + rowb * 256 + (((s * 2 + hi) ^ (rowb & 15)) << 4));
                const bf16x8 bw = *reinterpret_cast<const bf16x8*>(pk2 + ((size_t)s * 64 + l) * 8);
                a2 = __builtin_amdgcn_mfma_f32_32x32x16_bf16(ah, bw, a2, 0, 0, 0);
            }
            if (w == 0 && l31 < DOUT) {
                #pragma unroll
                for (int i = 0; i < 16; ++i) {
                    const int rowl = (i & 3) + 8 * (i >> 2) + 4 * hi;
                    const int grow = tile * 32 + rowl;
                    if (grow < nrows) out[(size_t)grow * DOUT + l31] = a2[i] + b2v;
                }
            }
        }
        __builtin_amdgcn_sched_barrier(0);
        waitvm<0>();                           // own G (+ bw/stores) drained
        __builtin_amdgcn_s_barrier();          // C: ob ready for all waves
        cur ^= 1;
    }
}

extern "C" void kernel_launch(void* const* d_in, const int* in_sizes, int n_in,
                              void* d_out, int out_size, void* d_ws, size_t ws_size,
                              hipStream_t stream) {
    const float* node = (const float*)d_in[0];
    const int* bidx = (const int*)d_in[1];
    const int* gidx = (const int*)d_in[2];
    const int* pidx = (const int*)d_in[3];
    const int* iidx = (const int*)d_in[4];

    const float* aw1 = (const float*)d_in[5];
    const float* ab1 = (const float*)d_in[6];
    const float* aw2 = (const float*)d_in[7];
    const float* ab2 = (const float*)d_in[8];
    const float* bw1 = (const float*)d_in[9];
    const float* bb1 = (const float*)d_in[10];
    const float* bw2 = (const float*)d_in[11];
    const float* bb2 = (const float*)d_in[12];
    const float* gw1 = (const float*)d_in[13];
    const float* gb1 = (const float*)d_in[14];
    const float* gw2 = (const float*)d_in[15];
    const float* gb2 = (const float*)d_in[16];
    const float* pw1 = (const float*)d_in[17];
    const float* pb1 = (const float*)d_in[18];
    const float* pw2 = (const float*)d_in[19];
    const float* pb2 = (const float*)d_in[20];
    const float* iw1 = (const float*)d_in[21];
    const float* ib1 = (const float*)d_in[22];
    const float* iw2 = (const float*)d_in[23];
    const float* ib2 = (const float*)d_in[24];

    const int N   = in_sizes[0] / 128;
    const int NB  = in_sizes[1] / 2;
    const int NAg = in_sizes[2] / 3;
    const int NP_ = in_sizes[3] / 4;
    const int NI  = in_sizes[4] / 4;

    float* out   = (float*)d_out;
    float* out_a = out;
    float* out_b = out_a + (size_t)N   * 2;
    float* out_g = out_b + (size_t)NB  * 2;
    float* out_p = out_g + (size_t)NAg * 2;
    float* out_i = out_p + (size_t)NP_ * 6;

    // ---- workspace layout (bf16 elements) ----
    unsigned short* nodeb = (unsigned short*)d_ws;
    size_t off = (size_t)N * 128;
    unsigned short* packA = nodeb + off; off += (size_t)128 * 128;
    unsigned short* packB = nodeb + off; off += (size_t)256 * 128;
    unsigned short* packG = nodeb + off; off += (size_t)384 * 128;
    unsigned short* packP = nodeb + off; off += (size_t)512 * 128;
    unsigned short* packI = nodeb + off; off += (size_t)512 * 128;
    unsigned short* pk2A  = nodeb + off; off += 4096;
    unsigned short* pk2B  = nodeb + off; off += 4096;
    unsigned short* pk2G  = nodeb + off; off += 4096;
    unsigned short* pk2P  = nodeb + off; off += 4096;
    unsigned short* pk2I  = nodeb + off; off += 4096;

    // ---- pre-pass ----
    {
        const int n4 = N * 128 / 4;
        conv_node<<<(n4 + PBLK - 1) / PBLK, PBLK, 0, stream>>>(node, nodeb, n4);
    }
    pack_w1<128><<<(128 * 128 + PBLK - 1) / PBLK, PBLK, 0, stream>>>(aw1, packA);
    pack_w1<256><<<(256 * 128 + PBLK - 1) / PBLK, PBLK, 0, stream>>>(bw1, packB);
    pack_w1<384><<<(384 * 128 + PBLK - 1) / PBLK, PBLK, 0, stream>>>(gw1, packG);
    pack_w1<512><<<(512 * 128 + PBLK - 1) / PBLK, PBLK, 0, stream>>>(pw1, packP);
    pack_w1<512><<<(512 * 128 + PBLK - 1) / PBLK, PBLK, 0, stream>>>(iw1, packI);
    pack_w2_all<<<(5 * 4096 + PBLK - 1) / PBLK, PBLK, 0, stream>>>(
        aw2, bw2, gw2, pw2, iw2, pk2A, pk2B, pk2G, pk2P, pk2I);

    // ---- term kernels (persistent grid-stride over 32-row tiles) ----
    const int nt0 = (N   + 31) / 32, g0 = nt0 < 1024 ? nt0 : 1024;
    const int nt1 = (NB  + 31) / 32, g1 = nt1 < 1024 ? nt1 : 1024;
    const int nt2 = (NAg + 31) / 32, g2 = nt2 <  768 ? nt2 :  768;
    const int nt3 = (NP_ + 31) / 32, g3 = nt3 <  512 ? nt3 :  512;
    const int nt4 = (NI  + 31) / 32, g4 = nt4 <  512 ? nt4 :  512;

    term_mfma<0><<<g0, 256, 0, stream>>>(nodeb, nullptr, packA, pk2A, ab1, ab2, out_a, N,   nt0);
    term_mfma<1><<<g1, 256, 0, stream>>>(nodeb, bidx,    packB, pk2B, bb1, bb2, out_b, NB,  nt1);
    term_mfma<2><<<g2, 256, 0, stream>>>(nodeb, gidx,    packG, pk2G, gb1, gb2, out_g, NAg, nt2);
    term_mfma<3><<<g3, 256, 0, stream>>>(nodeb, pidx,    packP, pk2P, pb1, pb2, out_p, NP_, nt3);
    term_mfma<4><<<g4, 256, 0, stream>>>(nodeb, iidx,    packI, pk2I, ib1, ib2, out_i, NI,  nt4);
}